// Round 13
// baseline (889.515 us; speedup 1.0000x reference)
//
#include <hip/hip_runtime.h>
#include <math.h>

// R13: taller GEMM tile + non-temporal A-stream.
// R12 evidence: VGPR=48 — compiler DELETED the explicit prefetch pipeline (gain came
// from B-reuse restructure; 77->64.6us, MfmaUtil 9%). Per-kt latency ~1340cy => B-loads
// are NOT L2-hit: each 32-row block re-reads all 311KB of Wt (1563x = 486MB/dispatch)
// while the 60.8MB S-stream thrashes L2.
// Fix: (1) 64x256 block tile: wave = 4 row-frags x 4 col-tiles (acc 64 VGPR),
//      16 MFMA per 8 loads (2x amortization), Wt traffic halves (782 blocks);
//      (2) A-loads via __builtin_nontemporal_load (S has zero cross-block reuse;
//      evict-first protects Wt residency in L2); (3) drop dead explicit pipeline.

// ---------------- problem constants ----------------
#define NENT     100000
#define NREL     474
#define DIM      200
#define NBASES   100
#define NEDGES   500000
#define NTRIPLES 200000

#define CHUNK    50000     // nodes per S-buffer chunk
#define NCHUNKS  2
#define SD       608       // S row stride (bf16): 600 data + 8 zero pad
#define KD       608       // Wt row stride (bf16)
#define NPAD     256       // padded N (16 col-tiles of 16; 4 tiles per wave)

// workspace byte offsets (1024-aligned regions)
#define OFF_R1    0UL           // 474*200*4 = 379200
#define OFF_R2    380928UL
#define OFF_R3    761856UL
#define OFF_R1B   1142784UL     // 474*200*2 = 189600 (bf16)
#define OFF_R2B   1335296UL
#define OFF_DEG   1527808UL     // 100000*4
#define OFF_CUR   1929216UL
#define OFF_CSR   2330624UL     // 100001*4
#define OFF_BSUM  2732032UL
#define OFF_BOFF  2736128UL
#define OFF_CSRC  2740224UL     // 500000*4
#define OFF_CRY   4743168UL     // 500000*4
#define OFF_WT1   6746112UL     // 256*608*2 = 311296
#define OFF_WT2   7057408UL
#define OFF_ENTB  7368704UL     // 100000*200*2 = 40,000,000
#define OFF_X1B   47369216UL    // 40,000,000 (bf16 layer-1 output)
#define OFF_SBUF  87369728UL    // 50000*608*2 = 60,800,000
#define OFF_X2    148169728UL   // 100000*200*4 = 80,000,000
// total = 228,169,728 bytes (~217.6 MiB)

typedef __attribute__((ext_vector_type(8))) short bf16x8;
typedef __attribute__((ext_vector_type(4))) float f32x4;

__device__ inline unsigned short f2bf(float f) {          // RNE
    unsigned u = __float_as_uint(f);
    return (unsigned short)((u + 0x7FFFu + ((u >> 16) & 1u)) >> 16);
}
__device__ inline float bf2f(unsigned short s) {
    return __uint_as_float(((unsigned)s) << 16);
}

// ---------------- tiny GEMM: C[MxN] = A[MxK] @ B[KxN] (relation chain, fp32) ----
__global__ __launch_bounds__(256) void k_small_gemm(
    const float* __restrict__ A, const float* __restrict__ B,
    float* __restrict__ C, int M, int K, int N)
{
    int tid = blockIdx.x * blockDim.x + threadIdx.x;
    if (tid >= M * N) return;
    int row = tid / N, col = tid - row * N;
    const float* a = A + (long)row * K;
    float acc = 0.f;
    int k = 0;
    for (; k + 4 <= K; k += 4) {
        acc = fmaf(a[k + 0], B[(k + 0) * N + col], acc);
        acc = fmaf(a[k + 1], B[(k + 1) * N + col], acc);
        acc = fmaf(a[k + 2], B[(k + 2) * N + col], acc);
        acc = fmaf(a[k + 3], B[(k + 3) * N + col], acc);
    }
    for (; k < K; ++k) acc = fmaf(a[k], B[k * N + col], acc);
    C[tid] = acc;
}

// ---------------- fp32 -> bf16 table (relations) ----------------
__global__ __launch_bounds__(256) void k_rb(const float* __restrict__ in,
                                            unsigned short* __restrict__ out, int n)
{
    int i = blockIdx.x * 256 + threadIdx.x;
    if (i < n) out[i] = f2bf(in[i]);
}

// ---------------- W[600][200] fp32 -> Wt[256][608] bf16 (transposed, padded) ----
__global__ __launch_bounds__(256) void k_wt(const float* __restrict__ W,
                                            unsigned short* __restrict__ Wt)
{
    int i = blockIdx.x * 256 + threadIdx.x;
    if (i >= NPAD * KD) return;
    int c = i / KD, k = i - c * KD;
    float v = (c < 200 && k < 600) ? W[k * 200 + c] : 0.f;
    Wt[i] = f2bf(v);
}

// ---------------- ent[entids] fp32 -> bf16 table ----------------
__global__ __launch_bounds__(256) void k_entb(const float4* __restrict__ ent,
                                              const int* __restrict__ ids,
                                              ushort4* __restrict__ out)
{
    int i = blockIdx.x * 256 + threadIdx.x;     // over NENT*50
    if (i >= NENT * 50) return;
    int node = i / 50, j = i - node * 50;
    float4 v = ent[(long)ids[node] * 50 + j];
    ushort4 o;
    o.x = f2bf(v.x); o.y = f2bf(v.y); o.z = f2bf(v.z); o.w = f2bf(v.w);
    out[i] = o;
}

// ---------------- CSR build ----------------
__global__ __launch_bounds__(256) void k_hist(const int* __restrict__ ei, int* __restrict__ deg)
{
    int e = blockIdx.x * blockDim.x + threadIdx.x;
    if (e >= NEDGES) return;
    atomicAdd(&deg[ei[NEDGES + e]], 1);
}

__global__ __launch_bounds__(256) void k_scanA(
    const int* __restrict__ deg, int* __restrict__ out, int* __restrict__ bsum)
{
    __shared__ int sd[256];
    int t = threadIdx.x, b = blockIdx.x;
    int base = b * 1024 + t * 4;
    int v0 = (base + 0 < NENT) ? deg[base + 0] : 0;
    int v1 = (base + 1 < NENT) ? deg[base + 1] : 0;
    int v2 = (base + 2 < NENT) ? deg[base + 2] : 0;
    int v3 = (base + 3 < NENT) ? deg[base + 3] : 0;
    int s = v0 + v1 + v2 + v3;
    sd[t] = s; __syncthreads();
    for (int off = 1; off < 256; off <<= 1) {
        int x = (t >= off) ? sd[t - off] : 0;
        __syncthreads();
        sd[t] += x;
        __syncthreads();
    }
    int excl = sd[t] - s;
    if (base + 0 < NENT) out[base + 0] = excl;
    if (base + 1 < NENT) out[base + 1] = excl + v0;
    if (base + 2 < NENT) out[base + 2] = excl + v0 + v1;
    if (base + 3 < NENT) out[base + 3] = excl + v0 + v1 + v2;
    if (t == 255) bsum[b] = sd[255];
}

__global__ __launch_bounds__(128) void k_scanB(
    const int* __restrict__ bsum, int* __restrict__ boff, int nb)
{
    __shared__ int sd[128];
    int t = threadIdx.x;
    int s = (t < nb) ? bsum[t] : 0;
    sd[t] = s; __syncthreads();
    for (int off = 1; off < 128; off <<= 1) {
        int x = (t >= off) ? sd[t - off] : 0;
        __syncthreads();
        sd[t] += x;
        __syncthreads();
    }
    if (t < nb) boff[t] = sd[t] - s;
}

__global__ __launch_bounds__(256) void k_scanC(int* __restrict__ csr, const int* __restrict__ boff)
{
    int t = threadIdx.x, b = blockIdx.x;
    int base = b * 1024 + t * 4;
    int add = boff[b];
    #pragma unroll
    for (int i = 0; i < 4; ++i)
        if (base + i < NENT) csr[base + i] += add;
    if (b == 0 && t == 0) csr[NENT] = NEDGES;
}

__global__ __launch_bounds__(256) void k_scatter(
    const int* __restrict__ ei, const int* __restrict__ et, const int* __restrict__ y,
    const int* __restrict__ csr, int* __restrict__ cur,
    int* __restrict__ csrc, int* __restrict__ cry)
{
    int e = blockIdx.x * blockDim.x + threadIdx.x;
    if (e >= NEDGES) return;
    int dst = ei[NEDGES + e];
    int pos = csr[dst] + atomicAdd(&cur[dst], 1);
    csrc[pos] = ei[e];
    cry[pos]  = et[e] | (y[e] << 16);
}

// ---------------- per-node bucketed message accumulation (all-bf16 gather) ----------
// one wave per node; lanes 0..49 each own 4 dims of the 200-dim row
__global__ __launch_bounds__(256) void k_accum(
    const unsigned short* __restrict__ xb,   // [NENT][200] bf16
    const unsigned short* __restrict__ rb,   // [NREL][200] bf16
    const int* __restrict__ csr, const int* __restrict__ csrc, const int* __restrict__ cry,
    unsigned short* __restrict__ S, int nodeBase)
{
    int wv   = (blockIdx.x * blockDim.x + threadIdx.x) >> 6;   // 0..CHUNK-1
    int lane = threadIdx.x & 63;
    unsigned short* srow = S + (long)wv * SD;
    if (lane >= 50) {
        if (lane == 50) {                    // zero the K-pad (cols 600..607)
            uint4 z; z.x = z.y = z.z = z.w = 0u;
            *(uint4*)(srow + 600) = z;
        }
        return;
    }
    int v = nodeBase + wv;
    int start = csr[v], end = csr[v + 1];
    float4 a0 = {0,0,0,0}, a1 = {0,0,0,0}, a2 = {0,0,0,0};
    for (int e = start; e < end; ++e) {
        int src = csrc[e];
        int ry  = cry[e];
        int rel = ry & 0xFFFF;
        int k   = ry >> 16;
        ushort4 xv = *(const ushort4*)(xb + (long)src * 200 + lane * 4);
        ushort4 rv = *(const ushort4*)(rb + (long)rel * 200 + lane * 4);
        float mx = bf2f(xv.x) + bf2f(rv.x), my = bf2f(xv.y) + bf2f(rv.y);
        float mz = bf2f(xv.z) + bf2f(rv.z), mw = bf2f(xv.w) + bf2f(rv.w);
        if (k == 0)      { a0.x += mx; a0.y += my; a0.z += mz; a0.w += mw; }
        else if (k == 1) { a1.x += mx; a1.y += my; a1.z += mz; a1.w += mw; }
        else             { a2.x += mx; a2.y += my; a2.z += mz; a2.w += mw; }
    }
    ushort4 o;
    o.x = f2bf(a0.x); o.y = f2bf(a0.y); o.z = f2bf(a0.z); o.w = f2bf(a0.w);
    *(ushort4*)(srow +   0 + lane * 4) = o;
    o.x = f2bf(a1.x); o.y = f2bf(a1.y); o.z = f2bf(a1.z); o.w = f2bf(a1.w);
    *(ushort4*)(srow + 200 + lane * 4) = o;
    o.x = f2bf(a2.x); o.y = f2bf(a2.y); o.z = f2bf(a2.z); o.w = f2bf(a2.w);
    *(ushort4*)(srow + 400 + lane * 4) = o;
}

// ---------------- MFMA GEMM: X = tanh( S[M x 608]bf16 @ Wt^T[608 x 256]bf16 ) ------
// Block = 4 waves, tile 64 rows x 256 cols. All waves share the 64 rows (4 row-frags);
// wave wid owns col-tiles wid*4..wid*4+3. Per kt: 4 nt A-loads + 4 B-loads feed
// 16 MFMAs (2x the load amortization of R12's 32-row tile). Wt traffic per dispatch
// halves (782 blocks x 311KB). A is nontemporal: zero cross-block reuse, evict-first
// keeps Wt L2-resident. acc = 4x4xf32x4 = 64 VGPR.
template<int OUTBF>
__global__ __launch_bounds__(256, 2) void k_gemm_mfma(
    const unsigned short* __restrict__ S, const unsigned short* __restrict__ Wt,
    void* __restrict__ Xout, int nrows, int rowBase)
{
    int wid  = threadIdx.x >> 6;          // 0..3 -> col-tile group
    int lane = threadIdx.x & 63;
    int l15  = lane & 15;
    int l4   = lane >> 4;
    int row0 = blockIdx.x * 64;

    const unsigned short* pa[4];
    #pragma unroll
    for (int rf = 0; rf < 4; ++rf) {
        int r = row0 + rf * 16 + l15;
        if (r >= nrows) r = nrows - 1;    // clamp reads only
        pa[rf] = S + (long)r * SD + l4 * 8;
    }
    const unsigned short* pw = Wt + (long)(wid * 64 + l15) * KD + l4 * 8;

    f32x4 acc[4][4] = {};                 // [row-frag][col-tile]
    #pragma unroll 1
    for (int kt = 0; kt < 19; ++kt) {
        int o = kt * 32;
        bf16x8 a0 = __builtin_nontemporal_load((const bf16x8*)(pa[0] + o));
        bf16x8 a1 = __builtin_nontemporal_load((const bf16x8*)(pa[1] + o));
        bf16x8 a2 = __builtin_nontemporal_load((const bf16x8*)(pa[2] + o));
        bf16x8 a3 = __builtin_nontemporal_load((const bf16x8*)(pa[3] + o));
        bf16x8 b0 = *(const bf16x8*)(pw + 0 * 16 * KD + o);
        bf16x8 b1 = *(const bf16x8*)(pw + 1 * 16 * KD + o);
        bf16x8 b2 = *(const bf16x8*)(pw + 2 * 16 * KD + o);
        bf16x8 b3 = *(const bf16x8*)(pw + 3 * 16 * KD + o);
        acc[0][0] = __builtin_amdgcn_mfma_f32_16x16x32_bf16(a0, b0, acc[0][0], 0, 0, 0);
        acc[1][0] = __builtin_amdgcn_mfma_f32_16x16x32_bf16(a1, b0, acc[1][0], 0, 0, 0);
        acc[2][0] = __builtin_amdgcn_mfma_f32_16x16x32_bf16(a2, b0, acc[2][0], 0, 0, 0);
        acc[3][0] = __builtin_amdgcn_mfma_f32_16x16x32_bf16(a3, b0, acc[3][0], 0, 0, 0);
        acc[0][1] = __builtin_amdgcn_mfma_f32_16x16x32_bf16(a0, b1, acc[0][1], 0, 0, 0);
        acc[1][1] = __builtin_amdgcn_mfma_f32_16x16x32_bf16(a1, b1, acc[1][1], 0, 0, 0);
        acc[2][1] = __builtin_amdgcn_mfma_f32_16x16x32_bf16(a2, b1, acc[2][1], 0, 0, 0);
        acc[3][1] = __builtin_amdgcn_mfma_f32_16x16x32_bf16(a3, b1, acc[3][1], 0, 0, 0);
        acc[0][2] = __builtin_amdgcn_mfma_f32_16x16x32_bf16(a0, b2, acc[0][2], 0, 0, 0);
        acc[1][2] = __builtin_amdgcn_mfma_f32_16x16x32_bf16(a1, b2, acc[1][2], 0, 0, 0);
        acc[2][2] = __builtin_amdgcn_mfma_f32_16x16x32_bf16(a2, b2, acc[2][2], 0, 0, 0);
        acc[3][2] = __builtin_amdgcn_mfma_f32_16x16x32_bf16(a3, b2, acc[3][2], 0, 0, 0);
        acc[0][3] = __builtin_amdgcn_mfma_f32_16x16x32_bf16(a0, b3, acc[0][3], 0, 0, 0);
        acc[1][3] = __builtin_amdgcn_mfma_f32_16x16x32_bf16(a1, b3, acc[1][3], 0, 0, 0);
        acc[2][3] = __builtin_amdgcn_mfma_f32_16x16x32_bf16(a2, b3, acc[2][3], 0, 0, 0);
        acc[3][3] = __builtin_amdgcn_mfma_f32_16x16x32_bf16(a3, b3, acc[3][3], 0, 0, 0);
    }

    #pragma unroll
    for (int rf = 0; rf < 4; ++rf) {
        #pragma unroll
        for (int nt = 0; nt < 4; ++nt) {
            int col = (wid * 4 + nt) * 16 + l15;
            bool cok = (col < DIM);
            #pragma unroll
            for (int i = 0; i < 4; ++i) {
                int r = row0 + rf * 16 + l4 * 4 + i;
                if (cok && r < nrows) {
                    float v = tanhf(acc[rf][nt][i]);
                    if (OUTBF) ((unsigned short*)Xout)[(long)(rowBase + r) * DIM + col] = f2bf(v);
                    else       ((float*)Xout)[(long)(rowBase + r) * DIM + col] = v;
                }
            }
        }
    }
}

// ---------------- row L2-normalize (in place, fp32) ----------------
__global__ __launch_bounds__(256) void k_norm(float4* __restrict__ x)
{
    int wv   = (blockIdx.x * blockDim.x + threadIdx.x) >> 6;
    int lane = threadIdx.x & 63;
    float4 v = {0,0,0,0};
    if (lane < 50) v = x[(long)wv * 50 + lane];
    float ss = v.x*v.x + v.y*v.y + v.z*v.z + v.w*v.w;
    for (int off = 1; off < 64; off <<= 1) ss += __shfl_xor(ss, off);
    float scale = 1.f / fmaxf(sqrtf(ss), 1e-12f);
    if (lane < 50) {
        v.x *= scale; v.y *= scale; v.z *= scale; v.w *= scale;
        x[(long)wv * 50 + lane] = v;
    }
}

// ---------------- triple scoring ----------------
__global__ __launch_bounds__(256) void k_score(
    const float4* __restrict__ x, const float4* __restrict__ r,
    const int* __restrict__ tri, float* __restrict__ out)
{
    int wv   = (blockIdx.x * blockDim.x + threadIdx.x) >> 6;
    int lane = threadIdx.x & 63;
    if (wv >= NTRIPLES) return;
    int h = tri[wv * 3 + 0], rel = tri[wv * 3 + 1], t = tri[wv * 3 + 2];
    float p = 0.f;
    if (lane < 50) {
        float4 hv = x[(long)h * 50 + lane];
        float4 rv = r[(long)rel * 50 + lane];
        float4 tv = x[(long)t * 50 + lane];
        p = fabsf(hv.x + rv.x - tv.x) + fabsf(hv.y + rv.y - tv.y)
          + fabsf(hv.z + rv.z - tv.z) + fabsf(hv.w + rv.w - tv.w);
    }
    for (int off = 1; off < 64; off <<= 1) p += __shfl_xor(p, off);
    if (lane == 0) out[wv] = 1.f / (1.f + expf(-p));
}

// ---------------- launch ----------------
extern "C" void kernel_launch(void* const* d_in, const int* in_sizes, int n_in,
                              void* d_out, int out_size, void* d_ws, size_t ws_size,
                              hipStream_t stream)
{
    const float* ent    = (const float*)d_in[0];
    const float* bases  = (const float*)d_in[1];
    const float* coeff  = (const float*)d_in[2];
    const float* w1     = (const float*)d_in[3];
    const float* rw1    = (const float*)d_in[4];
    const float* w2     = (const float*)d_in[5];
    const float* rw2    = (const float*)d_in[6];
    const int*   entids = (const int*)d_in[7];
    const int*   ei     = (const int*)d_in[8];
    const int*   etype  = (const int*)d_in[9];
    const int*   yv     = (const int*)d_in[10];
    const int*   tri    = (const int*)d_in[11];
    float* out = (float*)d_out;

    char* ws = (char*)d_ws;
    float* r1   = (float*)(ws + OFF_R1);
    float* r2   = (float*)(ws + OFF_R2);
    float* r3   = (float*)(ws + OFF_R3);
    unsigned short* r1b = (unsigned short*)(ws + OFF_R1B);
    unsigned short* r2b = (unsigned short*)(ws + OFF_R2B);
    int* deg    = (int*)(ws + OFF_DEG);
    int* cur    = (int*)(ws + OFF_CUR);
    int* csr    = (int*)(ws + OFF_CSR);
    int* bsum   = (int*)(ws + OFF_BSUM);
    int* boff   = (int*)(ws + OFF_BOFF);
    int* csrc   = (int*)(ws + OFF_CSRC);
    int* cry    = (int*)(ws + OFF_CRY);
    unsigned short* wt1  = (unsigned short*)(ws + OFF_WT1);
    unsigned short* wt2  = (unsigned short*)(ws + OFF_WT2);
    unsigned short* entb = (unsigned short*)(ws + OFF_ENTB);
    unsigned short* x1b  = (unsigned short*)(ws + OFF_X1B);
    unsigned short* Sbuf = (unsigned short*)(ws + OFF_SBUF);
    float* x2   = (float*)(ws + OFF_X2);

    hipMemsetAsync(ws + OFF_DEG, 0, OFF_CSR - OFF_DEG, stream);

    // relation chain (fp32): r1 = coeff@bases ; r2 = r1@rw1 ; r3 = r2@rw2
    {
        int tot = NREL * DIM;
        int nb = (tot + 255) / 256;
        k_small_gemm<<<nb, 256, 0, stream>>>(coeff, bases, r1, NREL, NBASES, DIM);
        k_small_gemm<<<nb, 256, 0, stream>>>(r1, rw1, r2, NREL, DIM, DIM);
        k_small_gemm<<<nb, 256, 0, stream>>>(r2, rw2, r3, NREL, DIM, DIM);
        k_rb<<<nb, 256, 0, stream>>>(r1, r1b, tot);
        k_rb<<<nb, 256, 0, stream>>>(r2, r2b, tot);
    }

    // weight transpose->bf16 (padded to 256 rows), entity table->bf16
    k_wt<<<(NPAD * KD + 255) / 256, 256, 0, stream>>>(w1, wt1);
    k_wt<<<(NPAD * KD + 255) / 256, 256, 0, stream>>>(w2, wt2);
    k_entb<<<(NENT * 50 + 255) / 256, 256, 0, stream>>>(
        (const float4*)ent, entids, (ushort4*)entb);

    // CSR by destination (shared by both layers)
    k_hist<<<(NEDGES + 255) / 256, 256, 0, stream>>>(ei, deg);
    int nScanBlocks = (NENT + 1023) / 1024;   // 98
    k_scanA<<<nScanBlocks, 256, 0, stream>>>(deg, csr, bsum);
    k_scanB<<<1, 128, 0, stream>>>(bsum, boff, nScanBlocks);
    k_scanC<<<nScanBlocks, 256, 0, stream>>>(csr, boff);
    k_scatter<<<(NEDGES + 255) / 256, 256, 0, stream>>>(ei, etype, yv, csr, cur, csrc, cry);

    int gblocks = (CHUNK + 63) / 64;     // 782 blocks (64-row tiles)

    // layer 1: x1b = bf16(tanh(bucketed-segsum(entb[src]+r1[et]) @ w1))
    for (int c = 0; c < NCHUNKS; ++c) {
        int base = c * CHUNK;
        k_accum<<<CHUNK * 64 / 256, 256, 0, stream>>>(entb, r1b,
                                                      csr, csrc, cry, Sbuf, base);
        k_gemm_mfma<1><<<gblocks, 256, 0, stream>>>(Sbuf, wt1, (void*)x1b, CHUNK, base);
    }
    // layer 2: x2 = tanh(bucketed-segsum(x1b[src]+r2[et]) @ w2)   (fp32 out)
    for (int c = 0; c < NCHUNKS; ++c) {
        int base = c * CHUNK;
        k_accum<<<CHUNK * 64 / 256, 256, 0, stream>>>(x1b, r2b,
                                                      csr, csrc, cry, Sbuf, base);
        k_gemm_mfma<0><<<gblocks, 256, 0, stream>>>(Sbuf, wt2, (void*)x2, CHUNK, base);
    }

    k_norm<<<NENT / 4, 256, 0, stream>>>((float4*)x2);
    k_score<<<(NTRIPLES + 3) / 4, 256, 0, stream>>>(
        (const float4*)x2, (const float4*)r3, tri, out);
}

// Round 14
// 729.020 us; speedup vs baseline: 1.2202x; 1.2202x over previous
//
#include <hip/hip_runtime.h>
#include <math.h>

// R14: single-variable revert — R13's 64x256 tile KEPT, nontemporal A-loads REMOVED.
// R13 evidence: FETCH doubled 33->63MB, dur 64.6->96.5us. nt-loads killed INTRA-block
// A-reuse (all 4 waves read the same 64 rows; evict-first forced ~4x refetch).
// The nt theory was backwards: S has no cross-block reuse but heavy intra-block reuse.
// Kept: 64-row tile (halves Wt L3 traffic 486->243MB/dispatch; R12's 64.6us matches
// ~486MB at ~10TB/s L3, so B-traffic is the structural cost).
// Prediction: FETCH back to ~33-40MB, GEMM ~45-55us, MfmaUtil 11-14%.

// ---------------- problem constants ----------------
#define NENT     100000
#define NREL     474
#define DIM      200
#define NBASES   100
#define NEDGES   500000
#define NTRIPLES 200000

#define CHUNK    50000     // nodes per S-buffer chunk
#define NCHUNKS  2
#define SD       608       // S row stride (bf16): 600 data + 8 zero pad
#define KD       608       // Wt row stride (bf16)
#define NPAD     256       // padded N (16 col-tiles of 16; 4 tiles per wave)

// workspace byte offsets (1024-aligned regions)
#define OFF_R1    0UL           // 474*200*4 = 379200
#define OFF_R2    380928UL
#define OFF_R3    761856UL
#define OFF_R1B   1142784UL     // 474*200*2 = 189600 (bf16)
#define OFF_R2B   1335296UL
#define OFF_DEG   1527808UL     // 100000*4
#define OFF_CUR   1929216UL
#define OFF_CSR   2330624UL     // 100001*4
#define OFF_BSUM  2732032UL
#define OFF_BOFF  2736128UL
#define OFF_CSRC  2740224UL     // 500000*4
#define OFF_CRY   4743168UL     // 500000*4
#define OFF_WT1   6746112UL     // 256*608*2 = 311296
#define OFF_WT2   7057408UL
#define OFF_ENTB  7368704UL     // 100000*200*2 = 40,000,000
#define OFF_X1B   47369216UL    // 40,000,000 (bf16 layer-1 output)
#define OFF_SBUF  87369728UL    // 50000*608*2 = 60,800,000
#define OFF_X2    148169728UL   // 100000*200*4 = 80,000,000
// total = 228,169,728 bytes (~217.6 MiB)

typedef __attribute__((ext_vector_type(8))) short bf16x8;
typedef __attribute__((ext_vector_type(4))) float f32x4;

__device__ inline unsigned short f2bf(float f) {          // RNE
    unsigned u = __float_as_uint(f);
    return (unsigned short)((u + 0x7FFFu + ((u >> 16) & 1u)) >> 16);
}
__device__ inline float bf2f(unsigned short s) {
    return __uint_as_float(((unsigned)s) << 16);
}

// ---------------- tiny GEMM: C[MxN] = A[MxK] @ B[KxN] (relation chain, fp32) ----
__global__ __launch_bounds__(256) void k_small_gemm(
    const float* __restrict__ A, const float* __restrict__ B,
    float* __restrict__ C, int M, int K, int N)
{
    int tid = blockIdx.x * blockDim.x + threadIdx.x;
    if (tid >= M * N) return;
    int row = tid / N, col = tid - row * N;
    const float* a = A + (long)row * K;
    float acc = 0.f;
    int k = 0;
    for (; k + 4 <= K; k += 4) {
        acc = fmaf(a[k + 0], B[(k + 0) * N + col], acc);
        acc = fmaf(a[k + 1], B[(k + 1) * N + col], acc);
        acc = fmaf(a[k + 2], B[(k + 2) * N + col], acc);
        acc = fmaf(a[k + 3], B[(k + 3) * N + col], acc);
    }
    for (; k < K; ++k) acc = fmaf(a[k], B[k * N + col], acc);
    C[tid] = acc;
}

// ---------------- fp32 -> bf16 table (relations) ----------------
__global__ __launch_bounds__(256) void k_rb(const float* __restrict__ in,
                                            unsigned short* __restrict__ out, int n)
{
    int i = blockIdx.x * 256 + threadIdx.x;
    if (i < n) out[i] = f2bf(in[i]);
}

// ---------------- W[600][200] fp32 -> Wt[256][608] bf16 (transposed, padded) ----
__global__ __launch_bounds__(256) void k_wt(const float* __restrict__ W,
                                            unsigned short* __restrict__ Wt)
{
    int i = blockIdx.x * 256 + threadIdx.x;
    if (i >= NPAD * KD) return;
    int c = i / KD, k = i - c * KD;
    float v = (c < 200 && k < 600) ? W[k * 200 + c] : 0.f;
    Wt[i] = f2bf(v);
}

// ---------------- ent[entids] fp32 -> bf16 table ----------------
__global__ __launch_bounds__(256) void k_entb(const float4* __restrict__ ent,
                                              const int* __restrict__ ids,
                                              ushort4* __restrict__ out)
{
    int i = blockIdx.x * 256 + threadIdx.x;     // over NENT*50
    if (i >= NENT * 50) return;
    int node = i / 50, j = i - node * 50;
    float4 v = ent[(long)ids[node] * 50 + j];
    ushort4 o;
    o.x = f2bf(v.x); o.y = f2bf(v.y); o.z = f2bf(v.z); o.w = f2bf(v.w);
    out[i] = o;
}

// ---------------- CSR build ----------------
__global__ __launch_bounds__(256) void k_hist(const int* __restrict__ ei, int* __restrict__ deg)
{
    int e = blockIdx.x * blockDim.x + threadIdx.x;
    if (e >= NEDGES) return;
    atomicAdd(&deg[ei[NEDGES + e]], 1);
}

__global__ __launch_bounds__(256) void k_scanA(
    const int* __restrict__ deg, int* __restrict__ out, int* __restrict__ bsum)
{
    __shared__ int sd[256];
    int t = threadIdx.x, b = blockIdx.x;
    int base = b * 1024 + t * 4;
    int v0 = (base + 0 < NENT) ? deg[base + 0] : 0;
    int v1 = (base + 1 < NENT) ? deg[base + 1] : 0;
    int v2 = (base + 2 < NENT) ? deg[base + 2] : 0;
    int v3 = (base + 3 < NENT) ? deg[base + 3] : 0;
    int s = v0 + v1 + v2 + v3;
    sd[t] = s; __syncthreads();
    for (int off = 1; off < 256; off <<= 1) {
        int x = (t >= off) ? sd[t - off] : 0;
        __syncthreads();
        sd[t] += x;
        __syncthreads();
    }
    int excl = sd[t] - s;
    if (base + 0 < NENT) out[base + 0] = excl;
    if (base + 1 < NENT) out[base + 1] = excl + v0;
    if (base + 2 < NENT) out[base + 2] = excl + v0 + v1;
    if (base + 3 < NENT) out[base + 3] = excl + v0 + v1 + v2;
    if (t == 255) bsum[b] = sd[255];
}

__global__ __launch_bounds__(128) void k_scanB(
    const int* __restrict__ bsum, int* __restrict__ boff, int nb)
{
    __shared__ int sd[128];
    int t = threadIdx.x;
    int s = (t < nb) ? bsum[t] : 0;
    sd[t] = s; __syncthreads();
    for (int off = 1; off < 128; off <<= 1) {
        int x = (t >= off) ? sd[t - off] : 0;
        __syncthreads();
        sd[t] += x;
        __syncthreads();
    }
    if (t < nb) boff[t] = sd[t] - s;
}

__global__ __launch_bounds__(256) void k_scanC(int* __restrict__ csr, const int* __restrict__ boff)
{
    int t = threadIdx.x, b = blockIdx.x;
    int base = b * 1024 + t * 4;
    int add = boff[b];
    #pragma unroll
    for (int i = 0; i < 4; ++i)
        if (base + i < NENT) csr[base + i] += add;
    if (b == 0 && t == 0) csr[NENT] = NEDGES;
}

__global__ __launch_bounds__(256) void k_scatter(
    const int* __restrict__ ei, const int* __restrict__ et, const int* __restrict__ y,
    const int* __restrict__ csr, int* __restrict__ cur,
    int* __restrict__ csrc, int* __restrict__ cry)
{
    int e = blockIdx.x * blockDim.x + threadIdx.x;
    if (e >= NEDGES) return;
    int dst = ei[NEDGES + e];
    int pos = csr[dst] + atomicAdd(&cur[dst], 1);
    csrc[pos] = ei[e];
    cry[pos]  = et[e] | (y[e] << 16);
}

// ---------------- per-node bucketed message accumulation (all-bf16 gather) ----------
// one wave per node; lanes 0..49 each own 4 dims of the 200-dim row
__global__ __launch_bounds__(256) void k_accum(
    const unsigned short* __restrict__ xb,   // [NENT][200] bf16
    const unsigned short* __restrict__ rb,   // [NREL][200] bf16
    const int* __restrict__ csr, const int* __restrict__ csrc, const int* __restrict__ cry,
    unsigned short* __restrict__ S, int nodeBase)
{
    int wv   = (blockIdx.x * blockDim.x + threadIdx.x) >> 6;   // 0..CHUNK-1
    int lane = threadIdx.x & 63;
    unsigned short* srow = S + (long)wv * SD;
    if (lane >= 50) {
        if (lane == 50) {                    // zero the K-pad (cols 600..607)
            uint4 z; z.x = z.y = z.z = z.w = 0u;
            *(uint4*)(srow + 600) = z;
        }
        return;
    }
    int v = nodeBase + wv;
    int start = csr[v], end = csr[v + 1];
    float4 a0 = {0,0,0,0}, a1 = {0,0,0,0}, a2 = {0,0,0,0};
    for (int e = start; e < end; ++e) {
        int src = csrc[e];
        int ry  = cry[e];
        int rel = ry & 0xFFFF;
        int k   = ry >> 16;
        ushort4 xv = *(const ushort4*)(xb + (long)src * 200 + lane * 4);
        ushort4 rv = *(const ushort4*)(rb + (long)rel * 200 + lane * 4);
        float mx = bf2f(xv.x) + bf2f(rv.x), my = bf2f(xv.y) + bf2f(rv.y);
        float mz = bf2f(xv.z) + bf2f(rv.z), mw = bf2f(xv.w) + bf2f(rv.w);
        if (k == 0)      { a0.x += mx; a0.y += my; a0.z += mz; a0.w += mw; }
        else if (k == 1) { a1.x += mx; a1.y += my; a1.z += mz; a1.w += mw; }
        else             { a2.x += mx; a2.y += my; a2.z += mz; a2.w += mw; }
    }
    ushort4 o;
    o.x = f2bf(a0.x); o.y = f2bf(a0.y); o.z = f2bf(a0.z); o.w = f2bf(a0.w);
    *(ushort4*)(srow +   0 + lane * 4) = o;
    o.x = f2bf(a1.x); o.y = f2bf(a1.y); o.z = f2bf(a1.z); o.w = f2bf(a1.w);
    *(ushort4*)(srow + 200 + lane * 4) = o;
    o.x = f2bf(a2.x); o.y = f2bf(a2.y); o.z = f2bf(a2.z); o.w = f2bf(a2.w);
    *(ushort4*)(srow + 400 + lane * 4) = o;
}

// ---------------- MFMA GEMM: X = tanh( S[M x 608]bf16 @ Wt^T[608 x 256]bf16 ) ------
// Block = 4 waves, tile 64 rows x 256 cols. All waves share the 64 rows (4 row-frags,
// plain loads -> intra-block L1/L2 reuse); wave wid owns col-tiles wid*4..wid*4+3.
// Per kt: 4 A-loads + 4 B-loads feed 16 MFMAs. Wt traffic: 782 blocks x 311KB = 243MB.
template<int OUTBF>
__global__ __launch_bounds__(256, 2) void k_gemm_mfma(
    const unsigned short* __restrict__ S, const unsigned short* __restrict__ Wt,
    void* __restrict__ Xout, int nrows, int rowBase)
{
    int wid  = threadIdx.x >> 6;          // 0..3 -> col-tile group
    int lane = threadIdx.x & 63;
    int l15  = lane & 15;
    int l4   = lane >> 4;
    int row0 = blockIdx.x * 64;

    const unsigned short* pa[4];
    #pragma unroll
    for (int rf = 0; rf < 4; ++rf) {
        int r = row0 + rf * 16 + l15;
        if (r >= nrows) r = nrows - 1;    // clamp reads only
        pa[rf] = S + (long)r * SD + l4 * 8;
    }
    const unsigned short* pw = Wt + (long)(wid * 64 + l15) * KD + l4 * 8;

    f32x4 acc[4][4] = {};                 // [row-frag][col-tile]
    #pragma unroll 1
    for (int kt = 0; kt < 19; ++kt) {
        int o = kt * 32;
        bf16x8 a0 = *(const bf16x8*)(pa[0] + o);
        bf16x8 a1 = *(const bf16x8*)(pa[1] + o);
        bf16x8 a2 = *(const bf16x8*)(pa[2] + o);
        bf16x8 a3 = *(const bf16x8*)(pa[3] + o);
        bf16x8 b0 = *(const bf16x8*)(pw + 0 * 16 * KD + o);
        bf16x8 b1 = *(const bf16x8*)(pw + 1 * 16 * KD + o);
        bf16x8 b2 = *(const bf16x8*)(pw + 2 * 16 * KD + o);
        bf16x8 b3 = *(const bf16x8*)(pw + 3 * 16 * KD + o);
        acc[0][0] = __builtin_amdgcn_mfma_f32_16x16x32_bf16(a0, b0, acc[0][0], 0, 0, 0);
        acc[1][0] = __builtin_amdgcn_mfma_f32_16x16x32_bf16(a1, b0, acc[1][0], 0, 0, 0);
        acc[2][0] = __builtin_amdgcn_mfma_f32_16x16x32_bf16(a2, b0, acc[2][0], 0, 0, 0);
        acc[3][0] = __builtin_amdgcn_mfma_f32_16x16x32_bf16(a3, b0, acc[3][0], 0, 0, 0);
        acc[0][1] = __builtin_amdgcn_mfma_f32_16x16x32_bf16(a0, b1, acc[0][1], 0, 0, 0);
        acc[1][1] = __builtin_amdgcn_mfma_f32_16x16x32_bf16(a1, b1, acc[1][1], 0, 0, 0);
        acc[2][1] = __builtin_amdgcn_mfma_f32_16x16x32_bf16(a2, b1, acc[2][1], 0, 0, 0);
        acc[3][1] = __builtin_amdgcn_mfma_f32_16x16x32_bf16(a3, b1, acc[3][1], 0, 0, 0);
        acc[0][2] = __builtin_amdgcn_mfma_f32_16x16x32_bf16(a0, b2, acc[0][2], 0, 0, 0);
        acc[1][2] = __builtin_amdgcn_mfma_f32_16x16x32_bf16(a1, b2, acc[1][2], 0, 0, 0);
        acc[2][2] = __builtin_amdgcn_mfma_f32_16x16x32_bf16(a2, b2, acc[2][2], 0, 0, 0);
        acc[3][2] = __builtin_amdgcn_mfma_f32_16x16x32_bf16(a3, b2, acc[3][2], 0, 0, 0);
        acc[0][3] = __builtin_amdgcn_mfma_f32_16x16x32_bf16(a0, b3, acc[0][3], 0, 0, 0);
        acc[1][3] = __builtin_amdgcn_mfma_f32_16x16x32_bf16(a1, b3, acc[1][3], 0, 0, 0);
        acc[2][3] = __builtin_amdgcn_mfma_f32_16x16x32_bf16(a2, b3, acc[2][3], 0, 0, 0);
        acc[3][3] = __builtin_amdgcn_mfma_f32_16x16x32_bf16(a3, b3, acc[3][3], 0, 0, 0);
    }

    #pragma unroll
    for (int rf = 0; rf < 4; ++rf) {
        #pragma unroll
        for (int nt = 0; nt < 4; ++nt) {
            int col = (wid * 4 + nt) * 16 + l15;
            bool cok = (col < DIM);
            #pragma unroll
            for (int i = 0; i < 4; ++i) {
                int r = row0 + rf * 16 + l4 * 4 + i;
                if (cok && r < nrows) {
                    float v = tanhf(acc[rf][nt][i]);
                    if (OUTBF) ((unsigned short*)Xout)[(long)(rowBase + r) * DIM + col] = f2bf(v);
                    else       ((float*)Xout)[(long)(rowBase + r) * DIM + col] = v;
                }
            }
        }
    }
}

// ---------------- row L2-normalize (in place, fp32) ----------------
__global__ __launch_bounds__(256) void k_norm(float4* __restrict__ x)
{
    int wv   = (blockIdx.x * blockDim.x + threadIdx.x) >> 6;
    int lane = threadIdx.x & 63;
    float4 v = {0,0,0,0};
    if (lane < 50) v = x[(long)wv * 50 + lane];
    float ss = v.x*v.x + v.y*v.y + v.z*v.z + v.w*v.w;
    for (int off = 1; off < 64; off <<= 1) ss += __shfl_xor(ss, off);
    float scale = 1.f / fmaxf(sqrtf(ss), 1e-12f);
    if (lane < 50) {
        v.x *= scale; v.y *= scale; v.z *= scale; v.w *= scale;
        x[(long)wv * 50 + lane] = v;
    }
}

// ---------------- triple scoring ----------------
__global__ __launch_bounds__(256) void k_score(
    const float4* __restrict__ x, const float4* __restrict__ r,
    const int* __restrict__ tri, float* __restrict__ out)
{
    int wv   = (blockIdx.x * blockDim.x + threadIdx.x) >> 6;
    int lane = threadIdx.x & 63;
    if (wv >= NTRIPLES) return;
    int h = tri[wv * 3 + 0], rel = tri[wv * 3 + 1], t = tri[wv * 3 + 2];
    float p = 0.f;
    if (lane < 50) {
        float4 hv = x[(long)h * 50 + lane];
        float4 rv = r[(long)rel * 50 + lane];
        float4 tv = x[(long)t * 50 + lane];
        p = fabsf(hv.x + rv.x - tv.x) + fabsf(hv.y + rv.y - tv.y)
          + fabsf(hv.z + rv.z - tv.z) + fabsf(hv.w + rv.w - tv.w);
    }
    for (int off = 1; off < 64; off <<= 1) p += __shfl_xor(p, off);
    if (lane == 0) out[wv] = 1.f / (1.f + expf(-p));
}

// ---------------- launch ----------------
extern "C" void kernel_launch(void* const* d_in, const int* in_sizes, int n_in,
                              void* d_out, int out_size, void* d_ws, size_t ws_size,
                              hipStream_t stream)
{
    const float* ent    = (const float*)d_in[0];
    const float* bases  = (const float*)d_in[1];
    const float* coeff  = (const float*)d_in[2];
    const float* w1     = (const float*)d_in[3];
    const float* rw1    = (const float*)d_in[4];
    const float* w2     = (const float*)d_in[5];
    const float* rw2    = (const float*)d_in[6];
    const int*   entids = (const int*)d_in[7];
    const int*   ei     = (const int*)d_in[8];
    const int*   etype  = (const int*)d_in[9];
    const int*   yv     = (const int*)d_in[10];
    const int*   tri    = (const int*)d_in[11];
    float* out = (float*)d_out;

    char* ws = (char*)d_ws;
    float* r1   = (float*)(ws + OFF_R1);
    float* r2   = (float*)(ws + OFF_R2);
    float* r3   = (float*)(ws + OFF_R3);
    unsigned short* r1b = (unsigned short*)(ws + OFF_R1B);
    unsigned short* r2b = (unsigned short*)(ws + OFF_R2B);
    int* deg    = (int*)(ws + OFF_DEG);
    int* cur    = (int*)(ws + OFF_CUR);
    int* csr    = (int*)(ws + OFF_CSR);
    int* bsum   = (int*)(ws + OFF_BSUM);
    int* boff   = (int*)(ws + OFF_BOFF);
    int* csrc   = (int*)(ws + OFF_CSRC);
    int* cry    = (int*)(ws + OFF_CRY);
    unsigned short* wt1  = (unsigned short*)(ws + OFF_WT1);
    unsigned short* wt2  = (unsigned short*)(ws + OFF_WT2);
    unsigned short* entb = (unsigned short*)(ws + OFF_ENTB);
    unsigned short* x1b  = (unsigned short*)(ws + OFF_X1B);
    unsigned short* Sbuf = (unsigned short*)(ws + OFF_SBUF);
    float* x2   = (float*)(ws + OFF_X2);

    hipMemsetAsync(ws + OFF_DEG, 0, OFF_CSR - OFF_DEG, stream);

    // relation chain (fp32): r1 = coeff@bases ; r2 = r1@rw1 ; r3 = r2@rw2
    {
        int tot = NREL * DIM;
        int nb = (tot + 255) / 256;
        k_small_gemm<<<nb, 256, 0, stream>>>(coeff, bases, r1, NREL, NBASES, DIM);
        k_small_gemm<<<nb, 256, 0, stream>>>(r1, rw1, r2, NREL, DIM, DIM);
        k_small_gemm<<<nb, 256, 0, stream>>>(r2, rw2, r3, NREL, DIM, DIM);
        k_rb<<<nb, 256, 0, stream>>>(r1, r1b, tot);
        k_rb<<<nb, 256, 0, stream>>>(r2, r2b, tot);
    }

    // weight transpose->bf16 (padded to 256 rows), entity table->bf16
    k_wt<<<(NPAD * KD + 255) / 256, 256, 0, stream>>>(w1, wt1);
    k_wt<<<(NPAD * KD + 255) / 256, 256, 0, stream>>>(w2, wt2);
    k_entb<<<(NENT * 50 + 255) / 256, 256, 0, stream>>>(
        (const float4*)ent, entids, (ushort4*)entb);

    // CSR by destination (shared by both layers)
    k_hist<<<(NEDGES + 255) / 256, 256, 0, stream>>>(ei, deg);
    int nScanBlocks = (NENT + 1023) / 1024;   // 98
    k_scanA<<<nScanBlocks, 256, 0, stream>>>(deg, csr, bsum);
    k_scanB<<<1, 128, 0, stream>>>(bsum, boff, nScanBlocks);
    k_scanC<<<nScanBlocks, 256, 0, stream>>>(csr, boff);
    k_scatter<<<(NEDGES + 255) / 256, 256, 0, stream>>>(ei, etype, yv, csr, cur, csrc, cry);

    int gblocks = (CHUNK + 63) / 64;     // 782 blocks (64-row tiles)

    // layer 1: x1b = bf16(tanh(bucketed-segsum(entb[src]+r1[et]) @ w1))
    for (int c = 0; c < NCHUNKS; ++c) {
        int base = c * CHUNK;
        k_accum<<<CHUNK * 64 / 256, 256, 0, stream>>>(entb, r1b,
                                                      csr, csrc, cry, Sbuf, base);
        k_gemm_mfma<1><<<gblocks, 256, 0, stream>>>(Sbuf, wt1, (void*)x1b, CHUNK, base);
    }
    // layer 2: x2 = tanh(bucketed-segsum(x1b[src]+r2[et]) @ w2)   (fp32 out)
    for (int c = 0; c < NCHUNKS; ++c) {
        int base = c * CHUNK;
        k_accum<<<CHUNK * 64 / 256, 256, 0, stream>>>(x1b, r2b,
                                                      csr, csrc, cry, Sbuf, base);
        k_gemm_mfma<0><<<gblocks, 256, 0, stream>>>(Sbuf, wt2, (void*)x2, CHUNK, base);
    }

    k_norm<<<NENT / 4, 256, 0, stream>>>((float4*)x2);
    k_score<<<(NTRIPLES + 3) / 4, 256, 0, stream>>>(
        (const float4*)x2, (const float4*)r3, tri, out);
}